// Round 5
// baseline (157.607 us; speedup 1.0000x reference)
//
#include <hip/hip_runtime.h>
#include <hip/hip_fp16.h>

// GraphSAGE 2-layer: N=50000, D=128, DEG=16. f16 pipeline.
// R5: column-sliced feature tables (4 x 3.2MB, 32 dims each) + XCD-pinned gather
//     (blockIdx%8 -> slice) so each XCD's random reads stay L2-resident.
//     5 launches: prep, gather1, gemm1, gather2, gemm2.
typedef _Float16 half8v __attribute__((ext_vector_type(8)));
typedef __attribute__((ext_vector_type(4))) float f32x4;

#define N_NODES 50000
#define D 128
#define DEG 16
#define K2 256     // 2*D
#define BM 64      // rows per GEMM block
#define SLS (N_NODES * 32)   // slice stride in elements (3.2 MB)

static __device__ __forceinline__ unsigned short f2h(float f) {
    return __half_as_ushort(__float2half(f));
}

// ---- prep: x -> f16 sliced ; W1,W2 -> f16 transposed (n-major) ----
__global__ void prep(const float* __restrict__ x, unsigned short* __restrict__ xh,
                     const float* __restrict__ W1, const float* __restrict__ W2,
                     unsigned short* __restrict__ Wt1, unsigned short* __restrict__ Wt2) {
    int b = blockIdx.x;
    int tid = threadIdx.x;
    if (b < 128) {
        int i = b * 256 + tid;               // [0, K2*D)
        int k = i / D, n = i % D;
        Wt1[n * K2 + k] = f2h(W1[i]);
        Wt2[n * K2 + k] = f2h(W2[i]);
    } else {
        int row = (b - 128) * 16 + (tid >> 4);   // 16 rows/block, 3125 blocks
        int p   = tid & 15;                       // 8-dim part
        const float* sp = x + (size_t)row * D + p * 8;
        float4 v0 = *(const float4*)(sp);
        float4 v1 = *(const float4*)(sp + 4);
        ushort4 o0, o1;
        o0.x = f2h(v0.x); o0.y = f2h(v0.y); o0.z = f2h(v0.z); o0.w = f2h(v0.w);
        o1.x = f2h(v1.x); o1.y = f2h(v1.y); o1.z = f2h(v1.z); o1.w = f2h(v1.w);
        int s = p >> 2;                           // slice 0..3
        unsigned short* dp = xh + (size_t)s * SLS + (size_t)row * 32 + (p & 3) * 8;
        *(ushort4*)(dp)     = o0;
        *(ushort4*)(dp + 4) = o1;
    }
}

// ---- gather: mean over neighbors, one 32-dim slice per XCD ----
__global__ __launch_bounds__(256, 4)
void gather_mean(const unsigned short* __restrict__ tb,   // sliced feats
                 const int* __restrict__ nbr,
                 unsigned short* __restrict__ meanbuf)    // N x D f16 row-major
{
    __shared__ int Nl[BM * DEG];     // 1024 ids for 64 rows
    const int tid  = threadIdx.x;
    const int xcd  = blockIdx.x & 7;
    const int bi   = blockIdx.x >> 3;
    const int slice = xcd & 3;
    const int half  = xcd >> 2;
    const int row0  = half * 25000 + bi * BM;
    const int rowEnd = half * 25000 + 25000;

    {   // stage indices
        int g = row0 * DEG + tid * 4;
        int gmax = N_NODES * DEG - 4;
        if (g > gmax) g = gmax;
        *(int4*)(Nl + tid * 4) = *(const int4*)(nbr + g);
    }
    __syncthreads();

    const int r = tid >> 2;          // 0..63
    const int q = tid & 3;           // 8-dim sub-slice
    int row = row0 + r;
    bool valid = row < rowEnd;
    if (!valid) row = rowEnd - 1;

    int4 i0 = *(const int4*)(Nl + r * 16);
    int4 i1 = *(const int4*)(Nl + r * 16 + 4);
    int4 i2 = *(const int4*)(Nl + r * 16 + 8);
    int4 i3 = *(const int4*)(Nl + r * 16 + 12);
    int ids[16] = { i0.x, i0.y, i0.z, i0.w, i1.x, i1.y, i1.z, i1.w,
                    i2.x, i2.y, i2.z, i2.w, i3.x, i3.y, i3.z, i3.w };

    const unsigned short* t = tb + (size_t)slice * SLS + q * 8;
    uint4 v[16];
    #pragma unroll
    for (int j = 0; j < 16; ++j)
        v[j] = *(const uint4*)(t + (size_t)ids[j] * 32);

    __half2 am[4];
    #pragma unroll
    for (int i = 0; i < 4; ++i) am[i] = __half2(__float2half(0.f), __float2half(0.f));
    #pragma unroll
    for (int j = 0; j < 16; ++j) {
        union { uint4 u; __half2 h[4]; } cv; cv.u = v[j];
        #pragma unroll
        for (int i = 0; i < 4; ++i) am[i] = __hadd2(am[i], cv.h[i]);
    }
    const __half2 sc = __half2(__float2half(0.0625f), __float2half(0.0625f));
    union { uint4 u; __half2 h[4]; } mv;
    #pragma unroll
    for (int i = 0; i < 4; ++i) mv.h[i] = __hmul2(am[i], sc);

    if (valid)
        *(uint4*)(meanbuf + (size_t)row * D + slice * 32 + q * 8) = mv.u;
}

// ---- GEMM: out = relu([self | mean] @ W + b); A staged from sliced self + mean ----
template <int OUT_SLICED_F16>
__global__ __launch_bounds__(256)
void gemm_sage(const unsigned short* __restrict__ tb,       // sliced self feats
               const unsigned short* __restrict__ meanbuf,  // N x D f16
               const unsigned short* __restrict__ wt,       // D x K2 f16 (n-major)
               const float* __restrict__ bias,
               void* __restrict__ out)
{
    __shared__ __align__(16) unsigned short Hl[BM * 264];
    const int tid  = threadIdx.x;
    const int row0 = blockIdx.x * BM;

    // stage A: 64 rows x 256 dims; 8 x 16B chunks per thread
    #pragma unroll
    for (int i = 0; i < 8; ++i) {
        int c   = tid + i * 256;
        int r   = c >> 5;
        int off = (c & 31) * 8;       // dim offset 0..248
        int row = row0 + r;
        if (row >= N_NODES) row = N_NODES - 1;
        uint4 d;
        if (off < D) {
            int s = off >> 5;
            d = *(const uint4*)(tb + (size_t)s * SLS + (size_t)row * 32 + (off & 31));
        } else {
            d = *(const uint4*)(meanbuf + (size_t)row * D + (off - D));
        }
        *(uint4*)(&Hl[r * 264 + off]) = d;
    }

    const int lane = tid & 63;
    const int w    = tid >> 6;
    const int quad = lane >> 4;
    const int l16  = lane & 15;
    const int n_base = w * 32;
    half8v bfrag[8][2];
    #pragma unroll
    for (int kk = 0; kk < 8; ++kk)
        #pragma unroll
        for (int ct = 0; ct < 2; ++ct)
            bfrag[kk][ct] = *(const half8v*)(wt + (n_base + ct * 16 + l16) * K2 + kk * 32 + quad * 8);

    __syncthreads();

    f32x4 acc[4][2];
    #pragma unroll
    for (int rt = 0; rt < 4; ++rt)
        #pragma unroll
        for (int ct = 0; ct < 2; ++ct)
            acc[rt][ct] = (f32x4){0.f, 0.f, 0.f, 0.f};

    #pragma unroll
    for (int kk = 0; kk < 8; ++kk) {
        half8v afrag[4];
        #pragma unroll
        for (int rt = 0; rt < 4; ++rt)
            afrag[rt] = *(const half8v*)(&Hl[(rt * 16 + l16) * 264 + kk * 32 + quad * 8]);
        #pragma unroll
        for (int rt = 0; rt < 4; ++rt)
            #pragma unroll
            for (int ct = 0; ct < 2; ++ct)
                acc[rt][ct] = __builtin_amdgcn_mfma_f32_16x16x32_f16(
                    afrag[rt], bfrag[kk][ct], acc[rt][ct], 0, 0, 0);
    }

    float bv0 = bias[n_base + l16];
    float bv1 = bias[n_base + 16 + l16];
    #pragma unroll
    for (int rt = 0; rt < 4; ++rt) {
        int grow_base = row0 + rt * 16 + quad * 4;
        #pragma unroll
        for (int r = 0; r < 4; ++r) {
            int grow = grow_base + r;
            if (grow >= N_NODES) continue;
            #pragma unroll
            for (int ct = 0; ct < 2; ++ct) {
                float vv = acc[rt][ct][r] + (ct ? bv1 : bv0);
                vv = vv > 0.f ? vv : 0.f;
                int col = n_base + ct * 16 + l16;
                if (OUT_SLICED_F16) {
                    int s = col >> 5;
                    ((unsigned short*)out)[(size_t)s * SLS + (size_t)grow * 32 + (col & 31)] = f2h(vv);
                } else {
                    ((float*)out)[(size_t)grow * D + col] = vv;
                }
            }
        }
    }
}

extern "C" void kernel_launch(void* const* d_in, const int* in_sizes, int n_in,
                              void* d_out, int out_size, void* d_ws, size_t ws_size,
                              hipStream_t stream) {
    const float* x  = (const float*)d_in[0];
    const int*   nb = (const int*)d_in[1];
    const float* W1 = (const float*)d_in[2];
    const float* b1 = (const float*)d_in[3];
    const float* W2 = (const float*)d_in[4];
    const float* b2 = (const float*)d_in[5];

    char* ws = (char*)d_ws;
    unsigned short* Wt1  = (unsigned short*)(ws);
    unsigned short* Wt2  = (unsigned short*)(ws + 65536);
    unsigned short* xh   = (unsigned short*)(ws + 131072);                    // 4 slices, 12.8MB
    unsigned short* h1   = (unsigned short*)(ws + 131072 + 12800000);         // 4 slices, 12.8MB
    unsigned short* mean = (unsigned short*)(ws + 131072 + 2 * 12800000);     // N x D, 12.8MB

    prep<<<128 + 3125, 256, 0, stream>>>(x, xh, W1, W2, Wt1, Wt2);

    const int ggrid = 8 * ((25000 + BM - 1) / BM);   // 8 * 391 = 3128
    const int mgrid = (N_NODES + BM - 1) / BM;       // 782

    gather_mean<<<ggrid, 256, 0, stream>>>(xh, nb, mean);
    gemm_sage<1><<<mgrid, 256, 0, stream>>>(xh, mean, Wt1, b1, h1);
    gather_mean<<<ggrid, 256, 0, stream>>>(h1, nb, mean);
    gemm_sage<0><<<mgrid, 256, 0, stream>>>(h1, mean, Wt2, b2, d_out);
}